// Round 9
// baseline (75.463 us; speedup 1.0000x reference)
//
#include <hip/hip_runtime.h>

// DataTermLayer: per-pixel optical-flow data-term update.
// Inputs (float32, each B*H*W = 16*1024*1024):
//   d_in[0]=I1, d_in[1]=I2, d_in[2]=u, d_in[3]=v
// Output: d_out = [u_next (N floats) | v_next (N floats)]
//
// Faithful-to-reference: grad_x := dy (vertical diff), grad_y := dx
// (horizontal diff) — the Python source swaps them.
//
// R9 = R8 compute core + fill overhaul:
//  - 128x16 tile, 512 threads, still 4 px/thread (R7's regression came
//    with 8px/thread VGPR pressure; avoided). Fill redundancy 2.13->1.56,
//    half the blocks/barriers. LDS 14 KB -> 4 blocks/CU wave capacity 100%.
//  - Interior blocks (73% of grid; block-uniform branch): VECTORIZED fill.
//    Row base tx0-4 is 16B-aligned, so f32x4 global loads + ds_write_b128,
//    ~2+2 ops/thread instead of 10 scalar loads + 10 scalar ds_writes.
//  - Edge blocks keep the clamped scalar fill (7 iters, guarded).
//  - u/v/I2 hoisted above fill; gradients via conflict-free ds_read_b128;
//    gathers scalar/unswizzled (statistical conflicts proven overlapped).

#define ALPHA 0.15f
#define IMG_H 1024
#define IMG_W 1024
#define TW 128
#define TH 16
#define HALO 4
#define LW 140          // 4 left halo + 128 + 8 right; rows 16B-aligned
#define LH 25           // 4 top halo + 16 + 5 bottom
#define LDS_N (LH * LW) // 3500
#define NTHR 512

typedef float f32x4 __attribute__((ext_vector_type(4)));

__global__ __launch_bounds__(NTHR) void dataterm_kernel(
        const float* __restrict__ I1,
        const float* __restrict__ I2,
        const float* __restrict__ u,
        const float* __restrict__ v,
        float* __restrict__ out_u,
        float* __restrict__ out_v) {
    const int W = IMG_W, H = IMG_H;
    const int t   = threadIdx.x;
    const int tx0 = blockIdx.x * TW;
    const int ty0 = blockIdx.y * TH;
    const int b   = blockIdx.z;

    const float* __restrict__ I1b = I1 + (size_t)b * (size_t)(H * W);

    __shared__ float S[LDS_N];

    // thread -> 4 consecutive pixels of one row (r in 0..15)
    const int r  = t >> 5;
    const int cb = (t & 31) << 2;
    const int h  = ty0 + r;
    const int wb = tx0 + cb;
    const int p  = (b * H + h) * W + wb;

    // --- register loads first: HBM latency overlaps the fill ---
    f32x4 u4  = *(const f32x4*)(u + p);
    f32x4 v4  = *(const f32x4*)(v + p);
    f32x4 i24 = *(const f32x4*)(I2 + p);

    // --- cooperative clamped tile fill ---
    const bool interior = (tx0 >= HALO) && (tx0 + LW - HALO <= W) &&
                          (ty0 >= HALO) && (ty0 + LH - HALO <= H);
    if (interior) {
        // vectorized: 875 f32x4 chunks (25 rows x 35), 16B-aligned both sides
        const float* gbase = I1b + (ty0 - HALO) * W + (tx0 - HALO);
        #pragma unroll
        for (int j = 0; j < 2; ++j) {
            int c = t + NTHR * j;                // 0..1023
            if (c < (LH * LW) / 4) {             // 875
                int ly  = c / (LW / 4);          // /35
                int lxc = c - ly * (LW / 4);
                f32x4 q = *(const f32x4*)(gbase + ly * W + 4 * lxc);
                *(f32x4*)(S + ly * LW + 4 * lxc) = q;
            }
        }
    } else {
        #pragma unroll
        for (int j = 0; j < 7; ++j) {
            int f = t + NTHR * j;                // 0..3583
            if (f < LDS_N) {
                int ly = f / LW;
                int lx = f - ly * LW;
                int gy = min(max(ty0 - HALO + ly, 0), H - 1);
                int gx = min(max(tx0 - HALO + lx, 0), W - 1);
                S[f] = I1b[gy * W + gx];
            }
        }
    }
    __syncthreads();

    // --- gradients from LDS via conflict-free ds_read_b128 ---
    const int cl = (HALO + r) * LW + HALO + cb;  // 16B-aligned
    f32x4 c4 = *(const f32x4*)(S + cl);
    f32x4 d4 = *(const f32x4*)(S + cl + LW);
    float c4r = S[cl + 4];

    float gyv[4] = { d4.x - c4.x, d4.y - c4.y, d4.z - c4.z, d4.w - c4.w };
    float gxv[4] = { c4.y - c4.x, c4.z - c4.y, c4.w - c4.z, c4r - c4.w };

    float uu[4] = { u4.x, u4.y, u4.z, u4.w };
    float vv[4] = { v4.x, v4.y, v4.z, v4.w };
    float i2[4] = { i24.x, i24.y, i24.z, i24.w };
    float ru[4], rv[4];

    #pragma unroll
    for (int i = 0; i < 4; ++i) {
        float x = (float)(wb + i) + 0.5f * uu[i];
        float y = (float)h        + 0.5f * vv[i];

        float x0f = floorf(x);
        float y0f = floorf(y);
        float wx1 = x - x0f;
        float wx0 = 1.0f - wx1;
        float wy1 = y - y0f;
        float wy0 = 1.0f - wy1;

        int x0 = (int)x0f, y0 = (int)y0f;
        int x1 = x0 + 1,   y1 = y0 + 1;

        float vx0 = (x0 >= 0 && x0 <= W - 1) ? 1.0f : 0.0f;
        float vx1 = (x1 >= 0 && x1 <= W - 1) ? 1.0f : 0.0f;
        float vy0 = (y0 >= 0 && y0 <= H - 1) ? 1.0f : 0.0f;
        float vy1 = (y1 >= 0 && y1 <= H - 1) ? 1.0f : 0.0f;

        int lx0 = x0 - tx0 + HALO;
        int ly0 = y0 - ty0 + HALO;

        float g00, g01, g10, g11;
        if ((unsigned)lx0 <= (unsigned)(LW - 2) &&
            (unsigned)ly0 <= (unsigned)(LH - 2)) {
            // in-tile (the always case): gather from LDS
            int q = ly0 * LW + lx0;
            g00 = S[q]          * (vy0 * vx0);
            g01 = S[q + 1]      * (vy0 * vx1);
            g10 = S[q + LW]     * (vy1 * vx0);
            g11 = S[q + LW + 1] * (vy1 * vx1);
        } else {
            // out-of-halo fallback (never taken for 0.5*N(0,1) flow)
            int x0c = min(max(x0, 0), W - 1);
            int x1c = min(max(x1, 0), W - 1);
            int y0c = min(max(y0, 0), H - 1);
            int y1c = min(max(y1, 0), H - 1);
            g00 = I1b[y0c * W + x0c] * (vy0 * vx0);
            g01 = I1b[y0c * W + x1c] * (vy0 * vx1);
            g10 = I1b[y1c * W + x0c] * (vy1 * vx0);
            g11 = I1b[y1c * W + x1c] * (vy1 * vx1);
        }

        float warped = g00 * (wy0 * wx0)
                     + g01 * (wy0 * wx1)
                     + g10 * (wy1 * wx0)
                     + g11 * (wy1 * wx1);

        float dataTerm = warped - i2[i];
        ru[i] = uu[i] - ALPHA * dataTerm * gyv[i];
        rv[i] = vv[i] - ALPHA * dataTerm * gxv[i];
    }

    f32x4 ruv = { ru[0], ru[1], ru[2], ru[3] };
    f32x4 rvv = { rv[0], rv[1], rv[2], rv[3] };
    __builtin_nontemporal_store(ruv, (f32x4*)(out_u + p));
    __builtin_nontemporal_store(rvv, (f32x4*)(out_v + p));
}

extern "C" void kernel_launch(void* const* d_in, const int* in_sizes, int n_in,
                              void* d_out, int out_size, void* d_ws, size_t ws_size,
                              hipStream_t stream) {
    const float* I1 = (const float*)d_in[0];
    const float* I2 = (const float*)d_in[1];
    const float* u  = (const float*)d_in[2];
    const float* v  = (const float*)d_in[3];

    int total = in_sizes[0];               // B*H*W = 16 * 1024 * 1024
    float* out_u = (float*)d_out;
    float* out_v = (float*)d_out + total;

    dim3 grid(IMG_W / TW, IMG_H / TH, total / (IMG_H * IMG_W));
    dataterm_kernel<<<grid, dim3(NTHR), 0, stream>>>(I1, I2, u, v, out_u, out_v);
}

// Round 10
// 71.941 us; speedup vs baseline: 1.0490x; 1.0490x over previous
//
#include <hip/hip_runtime.h>

// DataTermLayer: per-pixel optical-flow data-term update.
// Inputs (float32, each B*H*W = 16*1024*1024):
//   d_in[0]=I1, d_in[1]=I2, d_in[2]=u, d_in[3]=v
// Output: d_out = [u_next (N floats) | v_next (N floats)]
//
// Faithful-to-reference: grad_x := dy (vertical diff), grad_y := dx
// (horizontal diff) — the Python source swaps them.
//
// R10 = R8 (best, 65.9us: 256thr/TH=8, b128 gradients, hoisted u/v/I2,
// scalar unswizzled gathers) + ONLY the interior vectorized fill from R9
// (R9's regression came from the 512-thr/TH=16 structure, not the fill):
//  - interior blocks (73%, block-uniform): fill = ~2.3 f32x4 global loads
//    + ~2.3 ds_write_b128 per thread (595 16B chunks / 256 threads)
//    instead of 10 scalar loads + 10 scalar ds_writes + ~80 addr-VALU.
//  - edge blocks: R8's clamped scalar path (10 guarded iters).

#define ALPHA 0.15f
#define IMG_H 1024
#define IMG_W 1024
#define TW 128
#define TH 8
#define HALO 4
#define LW 140          // 4 left halo + 128 + 8 right; rows 16B-aligned
#define LH 17           // 4 top halo + 8 + 5 bottom
#define LDS_N 2560      // 10 * 256 >= LH*LW (=2380)
#define NCHUNK 595      // LH*LW/4 16B chunks

typedef float f32x4 __attribute__((ext_vector_type(4)));

__global__ __launch_bounds__(256) void dataterm_kernel(
        const float* __restrict__ I1,
        const float* __restrict__ I2,
        const float* __restrict__ u,
        const float* __restrict__ v,
        float* __restrict__ out_u,
        float* __restrict__ out_v) {
    const int W = IMG_W, H = IMG_H;
    const int t   = threadIdx.x;
    const int tx0 = blockIdx.x * TW;
    const int ty0 = blockIdx.y * TH;
    const int b   = blockIdx.z;

    const float* __restrict__ I1b = I1 + (size_t)b * (size_t)(H * W);

    __shared__ float S[LDS_N];

    // thread -> 4 consecutive pixels of one row
    const int r  = t >> 5;           // row within tile, 0..7
    const int cb = (t & 31) << 2;    // col base within tile, 0..124
    const int h  = ty0 + r;
    const int wb = tx0 + cb;
    const int p  = (b * H + h) * W + wb;

    // --- register loads first: HBM latency overlaps the fill ---
    f32x4 u4  = *(const f32x4*)(u + p);
    f32x4 v4  = *(const f32x4*)(v + p);
    f32x4 i24 = *(const f32x4*)(I2 + p);

    // --- cooperative clamped tile fill ---
    const bool interior = (tx0 >= HALO) && (tx0 + LW - HALO <= W) &&
                          (ty0 >= HALO) && (ty0 + LH - HALO <= H);
    if (interior) {
        // vectorized: 595 f32x4 chunks (17 rows x 35), 16B-aligned both sides
        const float* gbase = I1b + (ty0 - HALO) * W + (tx0 - HALO);
        #pragma unroll
        for (int j = 0; j < 3; ++j) {
            int c = t + 256 * j;                 // 0..767
            if (c < NCHUNK) {
                int ly  = c / (LW / 4);          // /35
                int lxc = c - ly * (LW / 4);
                f32x4 q = *(const f32x4*)(gbase + ly * W + 4 * lxc);
                *(f32x4*)(S + 4 * c) = q;        // ly*LW + 4*lxc == 4*c
            }
        }
    } else {
        #pragma unroll
        for (int j = 0; j < 10; ++j) {
            int f  = t + 256 * j;                // 0..2559
            int ly = f / LW;                     // 0..18
            int lx = f - ly * LW;
            int gy = min(max(ty0 - HALO + min(ly, LH - 1), 0), H - 1);
            int gx = min(max(tx0 - HALO + lx, 0), W - 1);
            S[f] = I1b[gy * W + gx];
        }
    }
    __syncthreads();

    // --- gradients from LDS via conflict-free ds_read_b128 ---
    const int cl = (HALO + r) * LW + HALO + cb;  // 16B-aligned
    f32x4 c4 = *(const f32x4*)(S + cl);
    f32x4 d4 = *(const f32x4*)(S + cl + LW);
    float c4r = S[cl + 4];

    float gyv[4] = { d4.x - c4.x, d4.y - c4.y, d4.z - c4.z, d4.w - c4.w };
    float gxv[4] = { c4.y - c4.x, c4.z - c4.y, c4.w - c4.z, c4r - c4.w };

    float uu[4] = { u4.x, u4.y, u4.z, u4.w };
    float vv[4] = { v4.x, v4.y, v4.z, v4.w };
    float i2[4] = { i24.x, i24.y, i24.z, i24.w };
    float ru[4], rv[4];

    #pragma unroll
    for (int i = 0; i < 4; ++i) {
        float x = (float)(wb + i) + 0.5f * uu[i];
        float y = (float)h        + 0.5f * vv[i];

        float x0f = floorf(x);
        float y0f = floorf(y);
        float wx1 = x - x0f;
        float wx0 = 1.0f - wx1;
        float wy1 = y - y0f;
        float wy0 = 1.0f - wy1;

        int x0 = (int)x0f, y0 = (int)y0f;
        int x1 = x0 + 1,   y1 = y0 + 1;

        float vx0 = (x0 >= 0 && x0 <= W - 1) ? 1.0f : 0.0f;
        float vx1 = (x1 >= 0 && x1 <= W - 1) ? 1.0f : 0.0f;
        float vy0 = (y0 >= 0 && y0 <= H - 1) ? 1.0f : 0.0f;
        float vy1 = (y1 >= 0 && y1 <= H - 1) ? 1.0f : 0.0f;

        int lx0 = x0 - tx0 + HALO;
        int ly0 = y0 - ty0 + HALO;

        float g00, g01, g10, g11;
        if ((unsigned)lx0 <= (unsigned)(LW - 2) &&
            (unsigned)ly0 <= (unsigned)(LH - 2)) {
            // in-tile (the always case): gather from LDS
            int q = ly0 * LW + lx0;
            g00 = S[q]          * (vy0 * vx0);
            g01 = S[q + 1]      * (vy0 * vx1);
            g10 = S[q + LW]     * (vy1 * vx0);
            g11 = S[q + LW + 1] * (vy1 * vx1);
        } else {
            // out-of-halo fallback (never taken for 0.5*N(0,1) flow)
            int x0c = min(max(x0, 0), W - 1);
            int x1c = min(max(x1, 0), W - 1);
            int y0c = min(max(y0, 0), H - 1);
            int y1c = min(max(y1, 0), H - 1);
            g00 = I1b[y0c * W + x0c] * (vy0 * vx0);
            g01 = I1b[y0c * W + x1c] * (vy0 * vx1);
            g10 = I1b[y1c * W + x0c] * (vy1 * vx0);
            g11 = I1b[y1c * W + x1c] * (vy1 * vx1);
        }

        float warped = g00 * (wy0 * wx0)
                     + g01 * (wy0 * wx1)
                     + g10 * (wy1 * wx0)
                     + g11 * (wy1 * wx1);

        float dataTerm = warped - i2[i];
        ru[i] = uu[i] - ALPHA * dataTerm * gyv[i];
        rv[i] = vv[i] - ALPHA * dataTerm * gxv[i];
    }

    f32x4 ruv = { ru[0], ru[1], ru[2], ru[3] };
    f32x4 rvv = { rv[0], rv[1], rv[2], rv[3] };
    __builtin_nontemporal_store(ruv, (f32x4*)(out_u + p));
    __builtin_nontemporal_store(rvv, (f32x4*)(out_v + p));
}

extern "C" void kernel_launch(void* const* d_in, const int* in_sizes, int n_in,
                              void* d_out, int out_size, void* d_ws, size_t ws_size,
                              hipStream_t stream) {
    const float* I1 = (const float*)d_in[0];
    const float* I2 = (const float*)d_in[1];
    const float* u  = (const float*)d_in[2];
    const float* v  = (const float*)d_in[3];

    int total = in_sizes[0];               // B*H*W = 16 * 1024 * 1024
    float* out_u = (float*)d_out;
    float* out_v = (float*)d_out + total;

    dim3 grid(IMG_W / TW, IMG_H / TH, total / (IMG_H * IMG_W));
    dataterm_kernel<<<grid, dim3(256), 0, stream>>>(I1, I2, u, v, out_u, out_v);
}

// Round 11
// 70.455 us; speedup vs baseline: 1.0711x; 1.0211x over previous
//
#include <hip/hip_runtime.h>

// DataTermLayer: per-pixel optical-flow data-term update.
// Inputs (float32, each B*H*W = 16*1024*1024):
//   d_in[0]=I1, d_in[1]=I2, d_in[2]=u, d_in[3]=v
// Output: d_out = [u_next (N floats) | v_next (N floats)]
//
// Faithful-to-reference: grad_x := dy (vertical diff), grad_y := dx
// (horizontal diff) — the Python source swaps them.
//
// R11: persistent ring-buffer strips. R8-R10 evidence: instruction mass
// is not the limiter; the [HBM-fill burst]->[barrier]->[LDS/VALU phase]
// oscillation is (no pipe >60% busy). Each block owns a 128-wide x
// 64-row column segment: 32-row LDS ring (17-row live window), and per
// 8-row strip it (a) issues next strip's 8 fill rows + u/v/I2 into
// REGISTERS, (b) computes the current strip from LDS, (c) only then
// ds_writes the staged rows (vmcnt wait lands after compute -> HBM
// latency hidden every iteration), (d) one barrier. Staged rows
// (sy+13..+20) are mod-32 disjoint from the read window (sy-4..+12).
// Fill redundancy 2.32x -> ~1.3x. Compute core identical to R8.

#define ALPHA 0.15f
#define IMG_H 1024
#define IMG_W 1024
#define TW 128
#define HALO 4
#define LW 140          // 4 left halo + 128 + 8 right; rows 16B-aligned
#define LH 17           // live window: sy-4 .. sy+12
#define RING 32         // ring rows (17 live + 8 staging + slack)
#define STRIPS 8        // strips (of 8 rows) per block

typedef float f32x4 __attribute__((ext_vector_type(4)));

__global__ __launch_bounds__(256) void dataterm_kernel(
        const float* __restrict__ I1,
        const float* __restrict__ I2,
        const float* __restrict__ u,
        const float* __restrict__ v,
        float* __restrict__ out_u,
        float* __restrict__ out_v) {
    const int W = IMG_W, H = IMG_H;
    const int t   = threadIdx.x;
    const int tx0 = blockIdx.x * TW;
    const int sy0 = blockIdx.y * (STRIPS * 8);
    const int b   = blockIdx.z;

    const float* __restrict__ I1b = I1 + (size_t)b * (size_t)(H * W);

    __shared__ float S[RING * LW];

    // thread -> 4 consecutive pixels of one row per strip
    const int r  = t >> 5;           // 0..7
    const int cb = (t & 31) << 2;    // 0..124
    const int wb = tx0 + cb;

    // --- current-strip u/v/I2 (strip 0), issued before prologue fill ---
    int p = (b * H + (sy0 + r)) * W + wb;
    f32x4 u4  = *(const f32x4*)(u + p);
    f32x4 v4  = *(const f32x4*)(v + p);
    f32x4 i24 = *(const f32x4*)(I2 + p);

    // --- prologue: fill live window rows sy0-4 .. sy0+12 (17 rows) ---
    #pragma unroll
    for (int j = 0; j < 10; ++j) {
        int f = t + 256 * j;
        if (f < LH * LW) {
            int ly = f / LW;
            int lx = f - ly * LW;
            int rp = sy0 - 4 + ly;                   // may be negative
            int gy = min(max(rp, 0), H - 1);
            int gx = min(max(tx0 - HALO + lx, 0), W - 1);
            S[(rp & (RING - 1)) * LW + lx] = I1b[gy * W + gx];
        }
    }
    __syncthreads();

    for (int it = 0; it < STRIPS; ++it) {
        const int sy = sy0 + it * 8;
        const int h  = sy + r;
        const bool last = (it == STRIPS - 1);

        // --- A. stage next strip: fill rows sy+13..sy+20 + u/v/I2 to regs ---
        float stg[5];
        f32x4 u4n = {}, v4n = {}, i2n = {};
        if (!last) {
            #pragma unroll
            for (int j = 0; j < 5; ++j) {
                int f = t + 256 * j;
                if (f < 8 * LW) {
                    int lyp = f / LW;
                    int lx  = f - lyp * LW;
                    int rp  = sy + 13 + lyp;
                    int gy  = min(rp, H - 1);
                    int gx  = min(max(tx0 - HALO + lx, 0), W - 1);
                    stg[j] = I1b[gy * W + gx];
                }
            }
            int pn = p + 8 * W;
            u4n = *(const f32x4*)(u + pn);
            v4n = *(const f32x4*)(v + pn);
            i2n = *(const f32x4*)(I2 + pn);
        }

        // --- B. compute current strip from LDS ring ---
        // gradients via conflict-free ds_read_b128 (ring-slot rows)
        const int slc = (h & (RING - 1)) * LW + HALO + cb;
        const int sld = ((h + 1) & (RING - 1)) * LW + HALO + cb;
        f32x4 c4 = *(const f32x4*)(S + slc);
        f32x4 d4 = *(const f32x4*)(S + sld);
        float c4r = S[slc + 4];

        float gyv[4] = { d4.x - c4.x, d4.y - c4.y, d4.z - c4.z, d4.w - c4.w };
        float gxv[4] = { c4.y - c4.x, c4.z - c4.y, c4.w - c4.z, c4r - c4.w };

        float uu[4] = { u4.x, u4.y, u4.z, u4.w };
        float vv[4] = { v4.x, v4.y, v4.z, v4.w };
        float i2[4] = { i24.x, i24.y, i24.z, i24.w };
        float ru[4], rv[4];

        #pragma unroll
        for (int i = 0; i < 4; ++i) {
            float x = (float)(wb + i) + 0.5f * uu[i];
            float y = (float)h        + 0.5f * vv[i];

            float x0f = floorf(x);
            float y0f = floorf(y);
            float wx1 = x - x0f;
            float wx0 = 1.0f - wx1;
            float wy1 = y - y0f;
            float wy0 = 1.0f - wy1;

            int x0 = (int)x0f, y0 = (int)y0f;
            int x1 = x0 + 1,   y1 = y0 + 1;

            float vx0 = (x0 >= 0 && x0 <= W - 1) ? 1.0f : 0.0f;
            float vx1 = (x1 >= 0 && x1 <= W - 1) ? 1.0f : 0.0f;
            float vy0 = (y0 >= 0 && y0 <= H - 1) ? 1.0f : 0.0f;
            float vy1 = (y1 >= 0 && y1 <= H - 1) ? 1.0f : 0.0f;

            int lx0 = x0 - tx0 + HALO;         // col in window
            int lyw = y0 - (sy - 4);           // row in live window

            float g00, g01, g10, g11;
            if ((unsigned)lx0 <= (unsigned)(LW - 2) &&
                (unsigned)lyw <= (unsigned)(LH - 2)) {
                // in-window (the always case): gather from LDS ring
                int q0 = (y0 & (RING - 1)) * LW + lx0;
                int q1 = (y1 & (RING - 1)) * LW + lx0;
                g00 = S[q0]     * (vy0 * vx0);
                g01 = S[q0 + 1] * (vy0 * vx1);
                g10 = S[q1]     * (vy1 * vx0);
                g11 = S[q1 + 1] * (vy1 * vx1);
            } else {
                // out-of-window fallback (never taken for 0.5*N(0,1) flow)
                int x0c = min(max(x0, 0), W - 1);
                int x1c = min(max(x1, 0), W - 1);
                int y0c = min(max(y0, 0), H - 1);
                int y1c = min(max(y1, 0), H - 1);
                g00 = I1b[y0c * W + x0c] * (vy0 * vx0);
                g01 = I1b[y0c * W + x1c] * (vy0 * vx1);
                g10 = I1b[y1c * W + x0c] * (vy1 * vx0);
                g11 = I1b[y1c * W + x1c] * (vy1 * vx1);
            }

            float warped = g00 * (wy0 * wx0)
                         + g01 * (wy0 * wx1)
                         + g10 * (wy1 * wx0)
                         + g11 * (wy1 * wx1);

            float dataTerm = warped - i2[i];
            ru[i] = uu[i] - ALPHA * dataTerm * gyv[i];
            rv[i] = vv[i] - ALPHA * dataTerm * gxv[i];
        }

        // --- C. stores ---
        f32x4 ruv = { ru[0], ru[1], ru[2], ru[3] };
        f32x4 rvv = { rv[0], rv[1], rv[2], rv[3] };
        __builtin_nontemporal_store(ruv, (f32x4*)(out_u + p));
        __builtin_nontemporal_store(rvv, (f32x4*)(out_v + p));

        // --- D. write staged rows (vmcnt wait lands here, after compute) ---
        if (!last) {
            #pragma unroll
            for (int j = 0; j < 5; ++j) {
                int f = t + 256 * j;
                if (f < 8 * LW) {
                    int lyp = f / LW;
                    int lx  = f - lyp * LW;
                    int rp  = sy + 13 + lyp;
                    S[(rp & (RING - 1)) * LW + lx] = stg[j];
                }
            }
        }

        // --- E. one barrier per strip ---
        __syncthreads();

        u4 = u4n; v4 = v4n; i24 = i2n;
        p += 8 * W;
    }
}

extern "C" void kernel_launch(void* const* d_in, const int* in_sizes, int n_in,
                              void* d_out, int out_size, void* d_ws, size_t ws_size,
                              hipStream_t stream) {
    const float* I1 = (const float*)d_in[0];
    const float* I2 = (const float*)d_in[1];
    const float* u  = (const float*)d_in[2];
    const float* v  = (const float*)d_in[3];

    int total = in_sizes[0];               // B*H*W = 16 * 1024 * 1024
    float* out_u = (float*)d_out;
    float* out_v = (float*)d_out + total;

    dim3 grid(IMG_W / TW, IMG_H / (STRIPS * 8), total / (IMG_H * IMG_W));
    dataterm_kernel<<<grid, dim3(256), 0, stream>>>(I1, I2, u, v, out_u, out_v);
}